// Round 1
// baseline (330.214 us; speedup 1.0000x reference)
//
#include <hip/hip_runtime.h>
#include <hip/hip_bf16.h>

namespace {
constexpr int NYg = 512, NXg = 512, NCELL = NYg * NXg;
constexpr int TPB = 1024;                  // 16 waves/block, 1 block/CU (LDS-bound)
constexpr int NBX = 8, NBY = 8, NBLK = 64; // 8x8 blocks of 64x64 cores
constexpr int BT = 64;                     // core edge
constexpr int W  = 10;                     // halo width -> 5 steps per exchange
constexpr int NT = BT + 2 * W;             // 84 tile edge
constexpr int ND = NT - 2;                 // 82 D-region edge
constexpr int NU = NT - 4;                 // 80 update-region edge
constexpr int NT2 = NT * NT, ND2 = ND * ND, NU2 = NU * NU;
constexpr int ITT = (NT2 + TPB - 1) / TPB; // 7
constexpr int ITD = (ND2 + TPB - 1) / TPB; // 7
constexpr int ITU = (NU2 + TPB - 1) / TPB; // 7
constexpr int ITC = (BT * BT) / TPB;       // 4
constexpr int NSTEP = 64;
constexpr int KG = 5;                      // steps per exchange group (== W/2)
constexpr int EOFF = 16;                   // fallback exchange-index offset
constexpr int NEX = 96;                    // exchange flag slots (spec<=12, fb<=79)
constexpr float I1HX = 0.01f;              // 1/DX
constexpr float I2HX = 0.005f;             // 1/(2DX)
constexpr double RGd = 910.0 * 9.81;
constexpr float PHYS_C = (float)(3.1e-17 * RGd * RGd * RGd);
// dt==0.1 exactly iff global maxD <= ~20000; conservative latch threshold:
constexpr float DSPEC = 19900.0f;
}

// module-owned globals (harness never touches __device__ globals)
__device__ float    g_H[2][NCELL];          // published core H, parity dbuf
__device__ unsigned g_sflag[NEX][NBLK];     // per-exchange ready flags
__device__ unsigned g_vflag[NBLK];          // verdict: 0=pending 1=ok 2=bad
__device__ unsigned g_bmax[NSTEP][NBLK];    // fallback per-step block max (~bits)
__device__ unsigned g_barC = 0, g_barG = 0; // init gen-barrier (replay-safe)

__device__ __forceinline__ void gen_barrier() {   // used ONCE per launch (init)
    __syncthreads();
    if (threadIdx.x == 0) {
        __threadfence();
        const unsigned gen = __hip_atomic_load(&g_barG, __ATOMIC_RELAXED,
                                               __HIP_MEMORY_SCOPE_AGENT);
        const unsigned arrived = __hip_atomic_fetch_add(&g_barC, 1u, __ATOMIC_ACQ_REL,
                                                        __HIP_MEMORY_SCOPE_AGENT);
        if (arrived == NBLK - 1) {
            __hip_atomic_store(&g_barC, 0u, __ATOMIC_RELAXED, __HIP_MEMORY_SCOPE_AGENT);
            __hip_atomic_fetch_add(&g_barG, 1u, __ATOMIC_RELEASE, __HIP_MEMORY_SCOPE_AGENT);
        } else {
            while (__hip_atomic_load(&g_barG, __ATOMIC_ACQUIRE,
                                     __HIP_MEMORY_SCOPE_AGENT) == gen)
                __builtin_amdgcn_s_sleep(2);
        }
        __threadfence();
    }
    __syncthreads();
}

__device__ __forceinline__ void coh_store(float* p, float v) {
    __hip_atomic_store(p, v, __ATOMIC_RELAXED, __HIP_MEMORY_SCOPE_AGENT);
}
__device__ __forceinline__ float coh_load(const float* p) {
    return __hip_atomic_load(p, __ATOMIC_RELAXED, __HIP_MEMORY_SCOPE_AGENT);
}

// ---- wire-format probe (R4-validated: wire is f32; probe kept for safety) ----
__device__ __forceinline__ bool wire_f32(const void* zt) {
    const unsigned short* u = (const unsigned short*)zt;
    unsigned short a16 = u[0], c16 = u[2];
    const float a = __bfloat162float(*(const __hip_bfloat16*)&a16);
    const float c = __bfloat162float(*(const __hip_bfloat16*)&c16);
    return !((a > 500.0f) && (a < 5000.0f) && (c > 500.0f) && (c < 5000.0f));
}
__device__ __forceinline__ float ldin(const void* p, int i, bool f32) {
    return f32 ? ((const float*)p)[i] : __bfloat162float(((const __hip_bfloat16*)p)[i]);
}
__device__ __forceinline__ void stout(void* p, int i, float v, bool f32) {
    if (f32) ((float*)p)[i] = v;
    else     ((__hip_bfloat16*)p)[i] = __float2bfloat16(v);
}

__global__ __launch_bounds__(TPB) void GlacierDynamicsCheckpointed_41412074668209_kernel(
    const void* __restrict__ Zt, const void* __restrict__ Hi,
    const void* __restrict__ Mk, const void* __restrict__ Pd,
    const void* __restrict__ Td, const void* __restrict__ Mf,
    void* __restrict__ Out)
{
    // 119 KB static LDS -> 1 block/CU (gfx950 supports up to 160 KiB/WG)
    __shared__ float Sl[NT2];                     // surface S = Z + H
    __shared__ float Hl[NT2];                     // thickness H (exact, owner bits)
    __shared__ float Zl[NT2];                     // bedrock Z (static)
    __shared__ float Dl[NT2];                     // diffusivity (per step)
    __shared__ float Ts[512], Ps[512], Js[512];   // sorted T | prefP | suffT
    __shared__ float wred[TPB / 64];
    __shared__ int   s_bad;

    const bool f32 = wire_f32(Zt);
    const int tid = threadIdx.x, b = blockIdx.x;
    const int by = b >> 3, bx = b & 7;
    const int ty0 = by * BT, tx0 = bx * BT;       // core origin in grid
    const float mf = ldin(Mf, 0, f32);

    float smbv[ITU], divv[ITU], mbv[ITU];         // per-thread update-region state

    // ---- init: zero sync slots (distributed; gen_barrier publishes) ----
    {
        const int gb = b * TPB + tid;
        constexpr int NS0 = NEX * NBLK;                   // 6144
        constexpr int NS1 = NS0 + NBLK;                   // 6208
        constexpr int NS2 = NS1 + NSTEP * NBLK;           // 10304
        if (gb < NS0)      ((unsigned*)g_sflag)[gb] = 0u;
        else if (gb < NS1) g_vflag[gb - NS0] = 0u;
        else if (gb < NS2) ((unsigned*)g_bmax)[gb - NS1] = 0u;
    }

    // ---- init: full extended tile (clamped) from inputs ----
    #pragma unroll
    for (int it = 0; it < ITT; ++it) {
        const int i = tid + it * TPB;
        if (i < NT2) {
            const int ly = i / NT, lx = i % NT;
            const int gy = min(max(ty0 - W + ly, 0), NYg - 1);
            const int gx = min(max(tx0 - W + lx, 0), NXg - 1);
            const int g = gy * NXg + gx;
            const float z = ldin(Zt, g, f32);
            const float h = ldin(Hi, g, f32);
            Zl[i] = z; Hl[i] = h; Sl[i] = z + h;
        }
    }
    #pragma unroll
    for (int it = 0; it < ITU; ++it) {
        const int i = tid + it * TPB;
        mbv[it] = 0.0f;
        if (i < NU2) {
            const int ly = 2 + i / NU, lx = 2 + i % NU;
            const int gy = min(max(ty0 - W + ly, 0), NYg - 1);
            const int gx = min(max(tx0 - W + lx, 0), NXg - 1);
            mbv[it] = ldin(Mk, gy * NXg + gx, f32);
        }
    }
    gen_barrier();                      // slots zeroed + everything visible

    // ---- degree-day SMB machinery (R5/R7/R8-proven numerics, 1024-thread port) ----
    int sortedYear = -1;
    auto tables = [&](int yi) {
        __syncthreads();
        if (tid < 512) {
            if (tid < 365) { Ts[tid] = ldin(Td, yi * 365 + tid, f32);
                             Ps[tid] = ldin(Pd, yi * 365 + tid, f32); }
            else           { Ts[tid] = 3.0e38f; Ps[tid] = 0.0f; }
        }
        __syncthreads();
        for (int kk = 2; kk <= 512; kk <<= 1)          // bitonic (T key, P payload)
            for (int j = kk >> 1; j > 0; j >>= 1) {
                if (tid < 512) {
                    const int i = tid, ixj = i ^ j;
                    if (ixj > i) {
                        const bool up = ((i & kk) == 0);
                        const float a = Ts[i], c = Ts[ixj];
                        if ((a > c) == up) {
                            Ts[i] = c; Ts[ixj] = a;
                            const float p = Ps[i]; Ps[i] = Ps[ixj]; Ps[ixj] = p;
                        }
                    }
                }
                __syncthreads();
            }
        if (tid < 512) Js[tid] = (tid < 365) ? Ts[tid] : 0.0f;
        __syncthreads();
        for (int off = 1; off < 512; off <<= 1) {      // prefix(P) | suffix(T)
            float p = 0.0f, q = 0.0f;
            if (tid < 512) { p = Ps[tid] + ((tid >= off) ? Ps[tid - off] : 0.0f);
                             q = Js[tid] + ((tid + off < 512) ? Js[tid + off] : 0.0f); }
            __syncthreads();
            if (tid < 512) { Ps[tid] = p; Js[tid] = q; }
            __syncthreads();
        }
    };
    auto smb_refresh = [&](int yi) {
        if (yi != sortedYear) { sortedYear = yi; tables(yi); }
        #pragma unroll
        for (int it = 0; it < ITU; ++it) {
            const int i = tid + it * TPB;
            if (i < NU2) {
                const int ly = 2 + i / NU, lx = 2 + i % NU;
                const float zs = Sl[ly * NT + lx];
                const float u = 0.006f * (zs - 1500.0f);   // GAMMA*(Zs-Z_REF)
                int lo = 0, hi = 365;                      // first idx with T > u
                while (lo < hi) { const int mid = (lo + hi) >> 1;
                                  if (Ts[mid] <= u) lo = mid + 1; else hi = mid; }
                const float acc = (lo > 0) ? Ps[lo - 1] : 0.0f;
                const float pdd = (lo < 365)
                    ? fmaxf(Js[lo] - u * (float)(365 - lo), 0.0f) : 0.0f;
                smbv[it] = (mbv[it] > 0.5f) ? (acc - mf * pdd) : -10.0f;
            }
        }
    };

    // ---- stencil passes on the extended tile (shared by spec + fallback) ----
    auto pass_D = [&]() {                 // D on interior [1,NT-2]^2
        #pragma unroll
        for (int it = 0; it < ITD; ++it) {
            const int i = tid + it * TPB;
            if (i < ND2) {
                const int ly = 1 + i / ND, lx = 1 + i % ND;
                const int gy = ty0 - W + ly, gx = tx0 - W + lx;   // may be off-grid
                const int cgy = min(max(gy, 0), NYg - 1), cgx = min(max(gx, 0), NXg - 1);
                const int si = ly * NT + lx;
                const float sc = Sl[si];
                const float gxv = (cgx == 0)       ? (Sl[si + 1] - sc) * I1HX
                                : (cgx == NXg - 1) ? (sc - Sl[si - 1]) * I1HX
                                                   : (Sl[si + 1] - Sl[si - 1]) * I2HX;
                const float gyv = (cgy == 0)       ? (Sl[si + NT] - sc) * I1HX
                                : (cgy == NYg - 1) ? (sc - Sl[si - NT]) * I1HX
                                                   : (Sl[si + NT] - Sl[si - NT]) * I2HX;
                const float h = sc - Zl[si];
                const float h2 = h * h;
                Dl[si] = (PHYS_C * (h2 * h2 * h)) * (gxv * gxv + gyv * gyv);
            }
        }
    };
    auto pass_div = [&]() {               // div into registers, region [2,NT-3]^2
        #pragma unroll
        for (int it = 0; it < ITU; ++it) {
            const int i = tid + it * TPB;
            divv[it] = 0.0f;
            if (i < NU2) {
                const int ly = 2 + i / NU, lx = 2 + i % NU;
                const int gy = ty0 - W + ly, gx = tx0 - W + lx;
                const int si = ly * NT + lx;
                const float sc = Sl[si], dc = Dl[si];
                float qxR = 0.0f, qxL = 0.0f, qyU = 0.0f, qyD = 0.0f;  // zero-flux bnd
                if (gx < NXg - 1) qxR = 0.5f * (Dl[si + 1] + dc)  * ((Sl[si + 1] - sc)  * I1HX);
                if (gx > 0)       qxL = 0.5f * (dc + Dl[si - 1])  * ((sc - Sl[si - 1])  * I1HX);
                if (gy < NYg - 1) qyU = 0.5f * (Dl[si + NT] + dc) * ((Sl[si + NT] - sc) * I1HX);
                if (gy > 0)       qyD = 0.5f * (dc + Dl[si - NT]) * ((sc - Sl[si - NT]) * I1HX);
                divv[it] = (qxR - qxL) * I1HX + (qyU - qyD) * I1HX;
            }
        }
    };
    auto pass_update = [&](float dt) {    // same expr everywhere -> halo bitwise == owner
        #pragma unroll
        for (int it = 0; it < ITU; ++it) {
            const int i = tid + it * TPB;
            if (i < NU2) {
                const int ly = 2 + i / NU, lx = 2 + i % NU;
                const int si = ly * NT + lx;
                const float hn = fmaxf(Hl[si] + dt * (smbv[it] + divv[it]), 0.0f);
                Hl[si] = hn;
                Sl[si] = Zl[si] + hn;
            }
        }
    };

    // ---- neighbor exchange: publish core H, flag, reload full halo ----
    auto exchange = [&](int e) {
        const int par = e & 1;            // parity dbuf: safe (flag chain proves drain)
        #pragma unroll
        for (int it = 0; it < ITC; ++it) {
            const int i = tid + it * TPB;
            const int r = i >> 6, c = i & 63;
            coh_store(&g_H[par][(ty0 + r) * NXg + tx0 + c], Hl[(W + r) * NT + W + c]);
        }
        __syncthreads();                  // drains vmcnt: publish retired
        if (tid == 0)
            __hip_atomic_store(&g_sflag[e][b], 1u, __ATOMIC_RELEASE,
                               __HIP_MEMORY_SCOPE_AGENT);
        if (tid < 8) {
            const int d = (tid < 4) ? tid : tid + 1;   // skip (0,0)
            const int nby = by + d / 3 - 1, nbx = bx + d % 3 - 1;
            if (nby >= 0 && nby < NBY && nbx >= 0 && nbx < NBX) {
                const int nb = nby * NBX + nbx;
                while (__hip_atomic_load(&g_sflag[e][nb], __ATOMIC_ACQUIRE,
                                         __HIP_MEMORY_SCOPE_AGENT) == 0u)
                    __builtin_amdgcn_s_sleep(1);
            }
        }
        __syncthreads();
        #pragma unroll
        for (int it = 0; it < ITT; ++it) {
            const int i = tid + it * TPB;
            if (i < NT2) {
                const int ly = i / NT, lx = i % NT;
                const bool core = (ly >= W) & (ly < W + BT) & (lx >= W) & (lx < W + BT);
                if (!core) {
                    const int gy = min(max(ty0 - W + ly, 0), NYg - 1);
                    const int gx = min(max(tx0 - W + lx, 0), NXg - 1);
                    const float h = coh_load(&g_H[par][gy * NXg + gx]);
                    Hl[i] = h; Sl[i] = Zl[i] + h;
                }
            }
        }
        __syncthreads();
    };

    auto snap_store = [&](bool h26, bool h57, bool h80) {
        #pragma unroll
        for (int it = 0; it < ITC; ++it) {
            const int i = tid + it * TPB;
            const int r = i >> 6, c = i & 63;
            const int g = (ty0 + r) * NXg + tx0 + c;
            const float h = Hl[(W + r) * NT + W + c];
            if (h26) stout(Out, g, h, f32);
            if (h57) stout(Out, NCELL + g, h, f32);
            if (h80) stout(Out, 2 * NCELL + g, h, f32);
        }
    };

    float t = 1979.0f, t_last = 0.0f;
    int prev_yi = 115;
    bool c26 = false, c57 = false, c80 = false;

    auto write_out = [&]() {
        #pragma unroll
        for (int it = 0; it < ITC; ++it) {
            const int i = tid + it * TPB;
            const int r = i >> 6, c = i & 63;
            const int g = (ty0 + r) * NXg + tx0 + c;
            stout(Out, 3 * NCELL + g, Hl[(W + r) * NT + W + c], f32);
            if (!c26) stout(Out, g, 0.0f, f32);
            if (!c57) stout(Out, NCELL + g, 0.0f, f32);
            if (!c80) stout(Out, 2 * NCELL + g, 0.0f, f32);
        }
    };

    smb_refresh(115);                     // year_idx(1979.0)=115, init surface
    __syncthreads();

    // ================= SPECULATIVE PHASE: dt == 0.1 assumed =================
    float dmax_all = 0.0f;                // latched while finite -> catches blowup
    int e = 0, step = 0;
    while (step < NSTEP && t < 1981.0f) {
        if (step > 0) exchange(++e);      // batched: one exchange per 5 steps
        #pragma unroll 1
        for (int j = 0; j < KG && step < NSTEP; ++j) {
            pass_D();
            __syncthreads();
            #pragma unroll
            for (int it = 0; it < ITC; ++it) {        // core-only validity latch
                const int i = tid + it * TPB;
                const int r = i >> 6, c = i & 63;
                dmax_all = fmaxf(dmax_all, Dl[(W + r) * NT + W + c]);
            }
            pass_div();
            __syncthreads();
            pass_update(0.1f);
            __syncthreads();
            const float tn = t + 0.1f;                // same float chain as reference
            const bool hit26 = !c26 && (tn >= 1926.0f);
            const bool hit57 = !c57 && (tn >= 1957.0f);
            const bool hit80 = !c80 && (tn >= 1980.0f);
            if (hit26 | hit57 | hit80) snap_store(hit26, hit57, hit80);
            c26 |= hit26; c57 |= hit57; c80 |= hit80;
            int yi = (int)floorf(tn - 1864.0f);
            yi = min(max(yi, 0), 127);
            const bool need = (yi != prev_yi) || (tn - t_last >= 10.0f);
            if (need) {
                t_last = tn; prev_yi = yi;
                if (tn < 1981.0f) smb_refresh(yi);
            }
            t = tn; ++step;
            if (t >= 1981.0f) break;
        }
    }

    // ---- spec outputs + verdict all-reduce (single end-of-run sync) ----
    write_out();
    for (int off = 32; off; off >>= 1) dmax_all = fmaxf(dmax_all, __shfl_down(dmax_all, off));
    if ((tid & 63) == 0) wred[tid >> 6] = dmax_all;
    __syncthreads();                      // wred filled; output stores drained
    if (tid == 0) {
        float m = wred[0];
        #pragma unroll
        for (int i = 1; i < TPB / 64; ++i) m = fmaxf(m, wred[i]);
        __hip_atomic_store(&g_vflag[b], (m < DSPEC) ? 1u : 2u,
                           __ATOMIC_RELEASE, __HIP_MEMORY_SCOPE_AGENT);
    }
    if (tid < 64) {
        unsigned v;
        while ((v = __hip_atomic_load(&g_vflag[tid], __ATOMIC_ACQUIRE,
                                      __HIP_MEMORY_SCOPE_AGENT)) == 0u)
            __builtin_amdgcn_s_sleep(1);
        const unsigned long long badmask = __ballot(v == 2u);
        if (tid == 0) s_bad = (badmask != 0ull) ? 1 : 0;
    }
    __syncthreads();
    if (s_bad == 0) return;               // speculation valid: done (expected path)

    // ================= EXACT FALLBACK: per-step dt all-reduce =================
    #pragma unroll
    for (int it = 0; it < ITT; ++it) {    // re-init H/S from inputs (Zl intact)
        const int i = tid + it * TPB;
        if (i < NT2) {
            const int ly = i / NT, lx = i % NT;
            const int gy = min(max(ty0 - W + ly, 0), NYg - 1);
            const int gx = min(max(tx0 - W + lx, 0), NXg - 1);
            const float h = ldin(Hi, gy * NXg + gx, f32);
            Hl[i] = h; Sl[i] = Zl[i] + h;
        }
    }
    __syncthreads();
    sortedYear = -1;
    smb_refresh(115);
    __syncthreads();
    t = 1979.0f; t_last = 0.0f; prev_yi = 115;
    c26 = c57 = c80 = false;

    #pragma unroll 1
    for (int st = 0; st < NSTEP; ++st) {
        if (st > 0) exchange(EOFF + st);  // full halo reload every step
        pass_D();
        __syncthreads();
        float dmax = 0.0f;
        #pragma unroll
        for (int it = 0; it < ITC; ++it) {
            const int i = tid + it * TPB;
            const int r = i >> 6, c = i & 63;
            dmax = fmaxf(dmax, Dl[(W + r) * NT + W + c]);
        }
        for (int off = 32; off; off >>= 1) dmax = fmaxf(dmax, __shfl_down(dmax, off));
        if ((tid & 63) == 0) wred[tid >> 6] = dmax;
        __syncthreads();
        if (tid == 0) {
            float m = wred[0];
            #pragma unroll
            for (int i = 1; i < TPB / 64; ++i) m = fmaxf(m, wred[i]);
            __hip_atomic_store(&g_bmax[st][b], ~__float_as_uint(m),
                               __ATOMIC_RELAXED, __HIP_MEMORY_SCOPE_AGENT);
        }
        pass_div();                       // overlaps the store/poll round-trip
        if (tid < 64) {
            unsigned v;
            while ((v = __hip_atomic_load(&g_bmax[st][tid], __ATOMIC_RELAXED,
                                          __HIP_MEMORY_SCOPE_AGENT)) == 0u)
                __builtin_amdgcn_s_sleep(1);
            float dv = __uint_as_float(~v);
            for (int off = 32; off; off >>= 1) dv = fmaxf(dv, __shfl_xor(dv, off));
            if (tid == 0) wred[0] = dv;
        }
        __syncthreads();
        const float maxD = wred[0];
        const float dt = fminf(0.1f, 2000.0f / (maxD + 1e-6f));   // CFL*dx^2 = 2000
        pass_update(dt);
        __syncthreads();
        const float tn = t + dt;
        const bool hit26 = !c26 && (tn >= 1926.0f);
        const bool hit57 = !c57 && (tn >= 1957.0f);
        const bool hit80 = !c80 && (tn >= 1980.0f);
        if (hit26 | hit57 | hit80) snap_store(hit26, hit57, hit80);
        c26 |= hit26; c57 |= hit57; c80 |= hit80;
        int yi = (int)floorf(tn - 1864.0f);
        yi = min(max(yi, 0), 127);
        const bool need = (yi != prev_yi) || (tn - t_last >= 10.0f);
        if (need) {
            t_last = tn; prev_yi = yi;
            if (tn < 1981.0f) smb_refresh(yi);
        }
        t = tn;
        if (t >= 1981.0f) break;          // uniform across grid (same dt chain)
    }
    write_out();                          // overwrite spec outputs with exact ones
}

extern "C" void kernel_launch(void* const* d_in, const int* in_sizes, int n_in,
                              void* d_out, int out_size, void* d_ws, size_t ws_size,
                              hipStream_t stream) {
    (void)in_sizes; (void)n_in; (void)out_size; (void)d_ws; (void)ws_size;
    const void* Zt = d_in[0];   // Z_topo
    const void* Hi = d_in[1];   // H_init
    const void* Mk = d_in[2];   // ice_mask
    // d_in[3] precip_tensor, d_in[4] T_m_lowest, d_in[5] T_s: unused by reference
    const void* Pd = d_in[6];   // P_daily
    const void* Td = d_in[7];   // T_daily
    const void* Mf = d_in[8];   // melt_factor
    hipLaunchKernelGGL(GlacierDynamicsCheckpointed_41412074668209_kernel,
                       dim3(NBLK), dim3(TPB), 0, stream,
                       Zt, Hi, Mk, Pd, Td, Mf, d_out);
}

// Round 2
// 278.588 us; speedup vs baseline: 1.1853x; 1.1853x over previous
//
#include <hip/hip_runtime.h>
#include <hip/hip_bf16.h>

namespace {
constexpr int NYg = 512, NXg = 512, NCELL = NYg * NXg;
constexpr int TPB = 1024;                  // 16 waves/block, 1 block/CU (LDS-bound)
constexpr int NBX = 8, NBY = 8, NBLK = 64; // 8x8 blocks of 64x64 cores
constexpr int BT = 64;                     // core edge
constexpr int W  = 10;                     // halo width -> 5 steps per exchange
constexpr int NT = BT + 2 * W;             // 84 tile edge
constexpr int NU = NT - 4;                 // 80 update-region edge
constexpr int NT2 = NT * NT, NU2 = NU * NU;
constexpr int ITT = (NT2 + TPB - 1) / TPB; // 7
constexpr int ITC = (BT * BT) / TPB;       // 4 (core cells / thread)
constexpr int NGH = 2628;                  // ghost-D cells: 82^2 - 64^2
constexpr int KG = 5;                      // steps per exchange group (== W/2)
constexpr int NSTEP = 64;
constexpr int NEX = 32;                    // exchange flag slots (<=13+refreshes)
constexpr float I1HX = 0.01f;              // 1/DX
constexpr float I2HX = 0.005f;             // 1/(2DX)
constexpr double RGd = 910.0 * 9.81;
constexpr float PHYS_C = (float)(3.1e-17 * RGd * RGd * RGd);
}

// module-owned globals (harness never touches __device__ globals)
__device__ float    g_H[2][NCELL];          // published core H, parity dbuf
__device__ unsigned g_sflag[NEX][NBLK];     // per-exchange ready flags
__device__ unsigned g_bmax[NSTEP][NBLK];    // per-step block max(D), ~bits (0=not ready)
__device__ unsigned g_barC = 0, g_barG = 0; // init gen-barrier (replay-safe)

__device__ __forceinline__ void gen_barrier() {   // used ONCE per launch (init)
    __syncthreads();
    if (threadIdx.x == 0) {
        __threadfence();
        const unsigned gen = __hip_atomic_load(&g_barG, __ATOMIC_RELAXED,
                                               __HIP_MEMORY_SCOPE_AGENT);
        const unsigned arrived = __hip_atomic_fetch_add(&g_barC, 1u, __ATOMIC_ACQ_REL,
                                                        __HIP_MEMORY_SCOPE_AGENT);
        if (arrived == NBLK - 1) {
            __hip_atomic_store(&g_barC, 0u, __ATOMIC_RELAXED, __HIP_MEMORY_SCOPE_AGENT);
            __hip_atomic_fetch_add(&g_barG, 1u, __ATOMIC_RELEASE, __HIP_MEMORY_SCOPE_AGENT);
        } else {
            while (__hip_atomic_load(&g_barG, __ATOMIC_ACQUIRE,
                                     __HIP_MEMORY_SCOPE_AGENT) == gen)
                __builtin_amdgcn_s_sleep(2);
        }
        __threadfence();
    }
    __syncthreads();
}

__device__ __forceinline__ void coh_store(float* p, float v) {
    __hip_atomic_store(p, v, __ATOMIC_RELAXED, __HIP_MEMORY_SCOPE_AGENT);
}
__device__ __forceinline__ float coh_load(const float* p) {
    return __hip_atomic_load(p, __ATOMIC_RELAXED, __HIP_MEMORY_SCOPE_AGENT);
}

// ---- wire-format probe (R4-validated: wire is f32; probe kept for safety) ----
__device__ __forceinline__ bool wire_f32(const void* zt) {
    const unsigned short* u = (const unsigned short*)zt;
    unsigned short a16 = u[0], c16 = u[2];
    const float a = __bfloat162float(*(const __hip_bfloat16*)&a16);
    const float c = __bfloat162float(*(const __hip_bfloat16*)&c16);
    return !((a > 500.0f) && (a < 5000.0f) && (c > 500.0f) && (c < 5000.0f));
}
__device__ __forceinline__ float ldin(const void* p, int i, bool f32) {
    return f32 ? ((const float*)p)[i] : __bfloat162float(((const __hip_bfloat16*)p)[i]);
}
__device__ __forceinline__ void stout(void* p, int i, float v, bool f32) {
    if (f32) ((float*)p)[i] = v;
    else     ((__hip_bfloat16*)p)[i] = __float2bfloat16(v);
}

// per-thread update-region state as NAMED SCALARS (no arrays -> no scratch risk)
#define FOR7(X) X(0) X(1) X(2) X(3) X(4) X(5) X(6)

__global__ __launch_bounds__(TPB) void GlacierDynamicsCheckpointed_41412074668209_kernel(
    const void* __restrict__ Zt, const void* __restrict__ Hi,
    const void* __restrict__ Mk, const void* __restrict__ Pd,
    const void* __restrict__ Td, const void* __restrict__ Mf,
    void* __restrict__ Out)
{
    // ~119 KB static LDS -> 1 block/CU (gfx950 allows up to 160 KiB/WG)
    __shared__ float Sl[NT2];                     // surface S = Z + H
    __shared__ float Hl[NT2];                     // thickness H (exact, owner bits)
    __shared__ float Zl[NT2];                     // bedrock Z (static)
    __shared__ float Dl[NT2];                     // diffusivity (per step)
    __shared__ float Ts[512], Ps[512], Js[512];   // sorted T | prefP | suffT
    __shared__ float wred[TPB / 64];

    const bool f32 = wire_f32(Zt);
    const int tid = threadIdx.x, b = blockIdx.x;
    const int by = b >> 3, bx = b & 7;
    const int ty0 = by * BT, tx0 = bx * BT;       // core origin in grid
    const float mf = ldin(Mf, 0, f32);

    float smb_0=0,smb_1=0,smb_2=0,smb_3=0,smb_4=0,smb_5=0,smb_6=0;
    float div_0=0,div_1=0,div_2=0,div_3=0,div_4=0,div_5=0,div_6=0;
    unsigned mbbits = 0;

    // ---- init: zero sync slots (distributed; gen_barrier publishes) ----
    {
        const int gb = b * TPB + tid;
        constexpr int NS0 = NEX * NBLK;                   // 2048
        constexpr int NS1 = NS0 + NSTEP * NBLK;           // 6144
        if (gb < NS0)      ((unsigned*)g_sflag)[gb] = 0u;
        else if (gb < NS1) ((unsigned*)g_bmax)[gb - NS0] = 0u;
    }

    // ---- init: full extended tile (clamped) from inputs ----
    #pragma unroll
    for (int it = 0; it < ITT; ++it) {
        const int i = tid + it * TPB;
        if (i < NT2) {
            const int ly = i / NT, lx = i % NT;
            const int gy = min(max(ty0 - W + ly, 0), NYg - 1);
            const int gx = min(max(tx0 - W + lx, 0), NXg - 1);
            const int g = gy * NXg + gx;
            const float z = ldin(Zt, g, f32);
            const float h = ldin(Hi, g, f32);
            Zl[i] = z; Hl[i] = h; Sl[i] = z + h;
        }
    }
    // ice mask -> packed bits (update region, clamped like R1-proven)
    #define MBJ(J) { const int i = tid + J * TPB; if (J < 6 || i < NU2) { \
        const int ly = 2 + i / NU, lx = 2 + i % NU; \
        const int gy = min(max(ty0 - W + ly, 0), NYg - 1); \
        const int gx = min(max(tx0 - W + lx, 0), NXg - 1); \
        if (ldin(Mk, gy * NXg + gx, f32) > 0.5f) mbbits |= (1u << J); } }
    FOR7(MBJ)

    // ---- degree-day SMB tables (R1-proven 1024-thread port) ----
    int sortedYear = -1;
    auto tables = [&](int yi) {
        __syncthreads();
        if (tid < 512) {
            if (tid < 365) { Ts[tid] = ldin(Td, yi * 365 + tid, f32);
                             Ps[tid] = ldin(Pd, yi * 365 + tid, f32); }
            else           { Ts[tid] = 3.0e38f; Ps[tid] = 0.0f; }
        }
        __syncthreads();
        for (int kk = 2; kk <= 512; kk <<= 1)          // bitonic (T key, P payload)
            for (int j = kk >> 1; j > 0; j >>= 1) {
                if (tid < 512) {
                    const int i = tid, ixj = i ^ j;
                    if (ixj > i) {
                        const bool up = ((i & kk) == 0);
                        const float a = Ts[i], c = Ts[ixj];
                        if ((a > c) == up) {
                            Ts[i] = c; Ts[ixj] = a;
                            const float p = Ps[i]; Ps[i] = Ps[ixj]; Ps[ixj] = p;
                        }
                    }
                }
                __syncthreads();
            }
        if (tid < 512) Js[tid] = (tid < 365) ? Ts[tid] : 0.0f;
        __syncthreads();
        for (int off = 1; off < 512; off <<= 1) {      // prefix(P) | suffix(T)
            float p = 0.0f, q = 0.0f;
            if (tid < 512) { p = Ps[tid] + ((tid >= off) ? Ps[tid - off] : 0.0f);
                             q = Js[tid] + ((tid + off < 512) ? Js[tid + off] : 0.0f); }
            __syncthreads();
            if (tid < 512) { Ps[tid] = p; Js[tid] = q; }
            __syncthreads();
        }
    };
    // per-cell SMB from current surface (binary search + prefix/suffix tables)
    #define SMBJ(J) { const int i = tid + J * TPB; if (J < 6 || i < NU2) { \
        const int ly = 2 + i / NU, lx = 2 + i % NU; \
        const float zs = Sl[ly * NT + lx]; \
        const float u = 0.006f * (zs - 1500.0f); \
        int lo = 0, hi = 365; \
        while (lo < hi) { const int mid = (lo + hi) >> 1; \
                          if (Ts[mid] <= u) lo = mid + 1; else hi = mid; } \
        const float acc = (lo > 0) ? Ps[lo - 1] : 0.0f; \
        const float pdd = (lo < 365) ? fmaxf(Js[lo] - u * (float)(365 - lo), 0.0f) : 0.0f; \
        smb_##J = ((mbbits >> J) & 1u) ? (acc - mf * pdd) : -10.0f; } }
    auto refresh = [&](int yi) {
        if (yi != sortedYear) { sortedYear = yi; tables(yi); }
        FOR7(SMBJ)
    };

    // ---- D at one tile cell (shared by core + ghost passes) ----
    auto computeD = [&](int ly, int lx) -> float {
        const int gy = ty0 - W + ly, gx = tx0 - W + lx;   // may be off-grid
        const int cgy = min(max(gy, 0), NYg - 1), cgx = min(max(gx, 0), NXg - 1);
        const int si = ly * NT + lx;
        const float sc = Sl[si];
        const float gxv = (cgx == 0)       ? (Sl[si + 1] - sc) * I1HX
                        : (cgx == NXg - 1) ? (sc - Sl[si - 1]) * I1HX
                                           : (Sl[si + 1] - Sl[si - 1]) * I2HX;
        const float gyv = (cgy == 0)       ? (Sl[si + NT] - sc) * I1HX
                        : (cgy == NYg - 1) ? (sc - Sl[si - NT]) * I1HX
                                           : (Sl[si + NT] - Sl[si - NT]) * I2HX;
        const float h = sc - Zl[si];
        const float h2 = h * h;
        return (PHYS_C * (h2 * h2 * h)) * (gxv * gxv + gyv * gyv);
    };

    #define DIVJ(J) { const int i = tid + J * TPB; if (J < 6 || i < NU2) { \
        const int ly = 2 + i / NU, lx = 2 + i % NU; \
        const int gy = ty0 - W + ly, gx = tx0 - W + lx; \
        const int si = ly * NT + lx; \
        const float sc = Sl[si], dc = Dl[si]; \
        float qxR = 0.0f, qxL = 0.0f, qyU = 0.0f, qyD = 0.0f; /* zero-flux bnd */ \
        if (gx < NXg - 1) qxR = 0.5f * (Dl[si + 1] + dc)  * ((Sl[si + 1] - sc)  * I1HX); \
        if (gx > 0)       qxL = 0.5f * (dc + Dl[si - 1])  * ((sc - Sl[si - 1])  * I1HX); \
        if (gy < NYg - 1) qyU = 0.5f * (Dl[si + NT] + dc) * ((Sl[si + NT] - sc) * I1HX); \
        if (gy > 0)       qyD = 0.5f * (dc + Dl[si - NT]) * ((sc - Sl[si - NT]) * I1HX); \
        div_##J = (qxR - qxL) * I1HX + (qyU - qyD) * I1HX; } }

    #define UPDJ(J) { const int i = tid + J * TPB; if (J < 6 || i < NU2) { \
        const int ly = 2 + i / NU, lx = 2 + i % NU; \
        const int si = ly * NT + lx; \
        const float hn = fmaxf(Hl[si] + dt * (smb_##J + div_##J), 0.0f); \
        Hl[si] = hn; \
        Sl[si] = Zl[si] + hn; } }

    // ---- neighbor exchange: publish core H, flag, reload full ghost ring ----
    auto exchange = [&](int e) {
        const int par = e & 1;            // 2-buffer + 1-deep flag chain: race-free
        #pragma unroll
        for (int it = 0; it < ITC; ++it) {
            const int i = tid + it * TPB;
            const int r = i >> 6, c = i & 63;
            coh_store(&g_H[par][(ty0 + r) * NXg + tx0 + c], Hl[(W + r) * NT + W + c]);
        }
        __syncthreads();                  // drains vmcnt: publish retired
        if (tid == 0)
            __hip_atomic_store(&g_sflag[e][b], 1u, __ATOMIC_RELEASE,
                               __HIP_MEMORY_SCOPE_AGENT);
        if (tid < 8) {
            const int d = (tid < 4) ? tid : tid + 1;   // skip (0,0)
            const int nby = by + d / 3 - 1, nbx = bx + d % 3 - 1;
            if (nby >= 0 && nby < NBY && nbx >= 0 && nbx < NBX) {
                const int nb = nby * NBX + nbx;
                while (__hip_atomic_load(&g_sflag[e][nb], __ATOMIC_ACQUIRE,
                                         __HIP_MEMORY_SCOPE_AGENT) == 0u)
                    __builtin_amdgcn_s_sleep(1);
            }
        }
        __syncthreads();
        #pragma unroll
        for (int it = 0; it < ITT; ++it) {
            const int i = tid + it * TPB;
            if (i < NT2) {
                const int ly = i / NT, lx = i % NT;
                const bool core = (ly >= W) & (ly < W + BT) & (lx >= W) & (lx < W + BT);
                if (!core) {
                    const int gy = min(max(ty0 - W + ly, 0), NYg - 1);
                    const int gx = min(max(tx0 - W + lx, 0), NXg - 1);
                    const float h = coh_load(&g_H[par][gy * NXg + gx]);
                    Hl[i] = h; Sl[i] = Zl[i] + h;
                }
            }
        }
        __syncthreads();
    };

    auto snap_store = [&](bool h26, bool h57, bool h80) {
        #pragma unroll
        for (int it = 0; it < ITC; ++it) {
            const int i = tid + it * TPB;
            const int r = i >> 6, c = i & 63;
            const int g = (ty0 + r) * NXg + tx0 + c;
            const float h = Hl[(W + r) * NT + W + c];
            if (h26) stout(Out, g, h, f32);
            if (h57) stout(Out, NCELL + g, h, f32);
            if (h80) stout(Out, 2 * NCELL + g, h, f32);
        }
    };

    gen_barrier();                        // sync slots zeroed everywhere
    refresh(115);                         // year_idx(1979.0)=115, init surface

    float t = 1979.0f, t_last = 0.0f;
    int prev_yi = 115, phase = 0, ec = 0;
    bool c26 = false, c57 = false, c80 = false;

    #pragma unroll 1
    for (int step = 0; step < NSTEP; ++step) {
        // ---- 0. ghost refill when validity margin exhausted (every KG steps) ----
        if (phase == KG) { exchange(++ec); phase = 0; }

        // ---- 1. core D + block max -> publish ASAP (starts the all-reduce RT) ----
        float dmax = 0.0f;
        #pragma unroll
        for (int it = 0; it < ITC; ++it) {
            const int i = tid + it * TPB;
            const int ly = W + (i >> 6), lx = W + (i & 63);
            const float D = computeD(ly, lx);
            Dl[ly * NT + lx] = D;
            dmax = fmaxf(dmax, D);
        }
        for (int off = 32; off; off >>= 1) dmax = fmaxf(dmax, __shfl_down(dmax, off));
        if ((tid & 63) == 0) wred[tid >> 6] = dmax;
        __syncthreads();                  // core D visible + wred ready
        if (tid == 0) {
            float m = wred[0];
            #pragma unroll
            for (int i2 = 1; i2 < TPB / 64; ++i2) m = fmaxf(m, wred[i2]);
            __hip_atomic_store(&g_bmax[step][b], ~__float_as_uint(m),
                               __ATOMIC_RELAXED, __HIP_MEMORY_SCOPE_AGENT);
        }

        // ---- 2. ghost-strip D — overlaps the all-reduce round trip ----
        #pragma unroll
        for (int it = 0; it < 3; ++it) {
            const int i = tid + it * TPB;
            if (i < NGH) {
                int ly, lx;
                if (i < 1476) {                          // rows 1..9 & 74..82, cols 1..82
                    const int half = (i >= 738);
                    const int k = i - (half ? 738 : 0);
                    ly = (half ? 74 : 1) + k / 82;
                    lx = 1 + k % 82;
                } else {                                  // rows 10..73, cols 1..9 & 74..82
                    const int k = i - 1476;
                    ly = 10 + k / 18;
                    const int c = k % 18;
                    lx = (c < 9) ? 1 + c : 65 + c;        // 65+9=74 .. 65+17=82
                }
                Dl[ly * NT + lx] = computeD(ly, lx);
            }
        }
        __syncthreads();                  // all D visible

        // ---- 3. dt-independent divergence into registers (more RT overlap) ----
        FOR7(DIVJ)

        // ---- 4. direct-read global max: wave 0 polls the 64 slots ----
        if (tid < 64) {
            unsigned v;
            while ((v = __hip_atomic_load(&g_bmax[step][tid], __ATOMIC_RELAXED,
                                          __HIP_MEMORY_SCOPE_AGENT)) == 0u)
                __builtin_amdgcn_s_sleep(1);
            float dv = __uint_as_float(~v);
            for (int off = 32; off; off >>= 1) dv = fmaxf(dv, __shfl_xor(dv, off));
            if (tid == 0) wred[0] = dv;
        }
        __syncthreads();
        const float dt = fminf(0.1f, 2000.0f / (wred[0] + 1e-6f));   // CFL*dx^2 = 2000

        // ---- 5. H/S update over full valid region ----
        FOR7(UPDJ)
        __syncthreads();
        ++phase;

        // ---- 6. time chain, snapshots, SMB refresh (globally uniform decisions) ----
        const float tn = t + dt;
        const bool hit26 = !c26 && (tn >= 1926.0f);
        const bool hit57 = !c57 && (tn >= 1957.0f);
        const bool hit80 = !c80 && (tn >= 1980.0f);
        if (hit26 | hit57 | hit80) snap_store(hit26, hit57, hit80);
        c26 |= hit26; c57 |= hit57; c80 |= hit80;

        int yi = (int)floorf(tn - 1864.0f);
        yi = min(max(yi, 0), 127);
        const bool need = (yi != prev_yi) || (tn - t_last >= 10.0f);
        if (need) {
            t_last = tn; prev_yi = yi;
            if (tn < 1981.0f) {
                // refresh reads Sl over the full update region: only valid at
                // phase<=1; otherwise re-validate the tile first (uniform choice)
                if (phase > 1) { exchange(++ec); phase = 0; }
                refresh(yi);
            }
        }
        t = tn;
        if (t >= 1981.0f) break;          // uniform across grid (same dt chain)
    }

    // ---- finals: H always; zeros for untriggered snapshots ----
    #pragma unroll
    for (int it = 0; it < ITC; ++it) {
        const int i = tid + it * TPB;
        const int r = i >> 6, c = i & 63;
        const int g = (ty0 + r) * NXg + tx0 + c;
        stout(Out, 3 * NCELL + g, Hl[(W + r) * NT + W + c], f32);
        if (!c26) stout(Out, g, 0.0f, f32);
        if (!c57) stout(Out, NCELL + g, 0.0f, f32);
        if (!c80) stout(Out, 2 * NCELL + g, 0.0f, f32);
    }
}

extern "C" void kernel_launch(void* const* d_in, const int* in_sizes, int n_in,
                              void* d_out, int out_size, void* d_ws, size_t ws_size,
                              hipStream_t stream) {
    (void)in_sizes; (void)n_in; (void)out_size; (void)d_ws; (void)ws_size;
    const void* Zt = d_in[0];   // Z_topo
    const void* Hi = d_in[1];   // H_init
    const void* Mk = d_in[2];   // ice_mask
    // d_in[3] precip_tensor, d_in[4] T_m_lowest, d_in[5] T_s: unused by reference
    const void* Pd = d_in[6];   // P_daily
    const void* Td = d_in[7];   // T_daily
    const void* Mf = d_in[8];   // melt_factor
    hipLaunchKernelGGL(GlacierDynamicsCheckpointed_41412074668209_kernel,
                       dim3(NBLK), dim3(TPB), 0, stream,
                       Zt, Hi, Mk, Pd, Td, Mf, d_out);
}